// Round 1
// baseline (2060.386 us; speedup 1.0000x reference)
//
#include <hip/hip_runtime.h>
#include <math.h>

// Problem constants
constexpr int S_    = 4096;
constexpr int Dm    = 896;
constexpr int NHd   = 14;
constexpr int NKVh  = 2;
constexpr int HDim  = 64;
constexpr int NQ    = NHd * HDim;        // 896
constexpr int NK    = NKVh * HDim;       // 128
constexpr int NTOT  = NQ + 2 * NK;       // 1152
constexpr int GROUPS = NHd / NKVh;       // 7
constexpr float L2B  = 19.9315685693241740873f;  // log2(1e6)

// ---------------------------------------------------------------------------
// Kernel 1: QKV GEMM + bias + RoPE (rotates q and k in-register via shfl_xor)
// grid 512 (8 rows each), block 256. Writes qkv_rot [S][1152] f32.
// col layout: [0,896) = q (head h = n/64), [896,1024) = k, [1024,1152) = v
// ---------------------------------------------------------------------------
__global__ __launch_bounds__(256) void qkv_rope_kernel(
    const float* __restrict__ hs,
    const float* __restrict__ Wq, const float* __restrict__ bq,
    const float* __restrict__ Wk, const float* __restrict__ bk,
    const float* __restrict__ Wv, const float* __restrict__ bv,
    float* __restrict__ qkv)
{
  __shared__ float hlds[Dm * 8];   // transposed: [d][r]
  const int tid  = threadIdx.x;
  const int row0 = blockIdx.x * 8;

  for (int f = tid; f < 8 * Dm; f += 256) {
    int r = f / Dm;
    int d = f - r * Dm;
    hlds[d * 8 + r] = hs[(row0 + r) * Dm + d];
  }
  __syncthreads();

  // per-thread columns n = tid + 256*i, i = 0..4 (i==4 valid only tid<128)
  const float* wp[5];
  int wstride[5];
  bool valid[5];
  float acc[5][8];
  #pragma unroll
  for (int i = 0; i < 5; i++) {
    int n = tid + 256 * i;
    valid[i] = (n < NTOT);
    float b = 0.f;
    if (n < NQ)            { wp[i] = Wq + n;              wstride[i] = NQ; b = bq[n]; }
    else if (n < NQ + NK)  { wp[i] = Wk + (n - NQ);       wstride[i] = NK; b = bk[n - NQ]; }
    else if (n < NTOT)     { wp[i] = Wv + (n - NQ - NK);  wstride[i] = NK; b = bv[n - NQ - NK]; }
    else                   { wp[i] = Wv; wstride[i] = 0; }
    #pragma unroll
    for (int r = 0; r < 8; r++) acc[i][r] = b;
  }

  #pragma unroll 4
  for (int d = 0; d < Dm; d++) {
    float4 h0 = *(const float4*)&hlds[d * 8];
    float4 h1 = *(const float4*)&hlds[d * 8 + 4];
    float hv[8] = {h0.x, h0.y, h0.z, h0.w, h1.x, h1.y, h1.z, h1.w};
    #pragma unroll
    for (int i = 0; i < 5; i++) {
      float w = valid[i] ? wp[i][d * wstride[i]] : 0.f;
      #pragma unroll
      for (int r = 0; r < 8; r++) acc[i][r] = fmaf(hv[r], w, acc[i][r]);
    }
  }

  // RoPE on iterations 0..3 (all columns < 1024 are q or k); all lanes active.
  #pragma unroll
  for (int i = 0; i < 4; i++) {
    int n    = tid + 256 * i;
    int idim = n & 63;
    int j    = n & 31;
    float freq = exp2f(-(float)j * (L2B / 32.0f));
    float sgn  = (idim < 32) ? -1.f : 1.f;
    #pragma unroll
    for (int r = 0; r < 8; r++) {
      float partner = __shfl_xor(acc[i][r], 32, 64);
      float th = (float)(row0 + r) * freq;
      float sn, cs;
      sincosf(th, &sn, &cs);
      qkv[(row0 + r) * NTOT + n] = acc[i][r] * cs + sgn * partner * sn;
    }
  }
  // V passthrough (iteration 4)
  {
    int n = tid + 1024;
    if (n < NTOT) {
      #pragma unroll
      for (int r = 0; r < 8; r++)
        qkv[(row0 + r) * NTOT + n] = acc[4][r];
    }
  }
}

// ---------------------------------------------------------------------------
// Kernel 2: flash attention (f32, online softmax), causal.
// grid (64 qtiles, 14 heads), block 256. 4 threads per query row; each thread
// owns a 16-wide slice of Q and O in registers. K/V tiles staged in LDS.
// Writes attn [S][896] (row layout: head h occupies cols h*64..h*64+63).
// ---------------------------------------------------------------------------
__global__ __launch_bounds__(256) void flash_kernel(
    const float* __restrict__ qkv, float* __restrict__ attn)
{
  __shared__ float Ks[64 * 68];
  __shared__ float Vs[64 * 68];

  const int tid = threadIdx.x;
  const int h   = blockIdx.y;
  const int kv  = h / GROUPS;
  const int qt  = blockIdx.x;
  const int q0  = qt * 64;
  const int q   = tid >> 2;
  const int c4  = tid & 3;
  const int d0  = c4 * 16;
  const int qg  = q0 + q;

  const int kbase = NQ + kv * HDim;        // K column offset in qkv row
  const int vbase = NQ + NK + kv * HDim;   // V column offset

  // Q slice into registers, pre-scaled by 1/sqrt(HD)
  float4 Qr[4];
  {
    const float* qp = qkv + qg * NTOT + h * HDim + d0;
    #pragma unroll
    for (int jj = 0; jj < 4; jj++) {
      float4 t = *(const float4*)(qp + 4 * jj);
      t.x *= 0.125f; t.y *= 0.125f; t.z *= 0.125f; t.w *= 0.125f;
      Qr[jj] = t;
    }
  }

  float o[16];
  #pragma unroll
  for (int jj = 0; jj < 16; jj++) o[jj] = 0.f;
  float m = -3.0e38f, l = 0.f;

  for (int kt = 0; kt <= qt; kt++) {
    // stage K and V 64x64 tiles (stride 68 floats)
    #pragma unroll
    for (int p = 0; p < 4; p++) {
      int idx = tid + 256 * p;          // float4 units, 0..1023
      int row = idx >> 4;
      int c   = idx & 15;
      const float* src = &qkv[(kt * 64 + row) * NTOT];
      *(float4*)&Ks[row * 68 + c * 4] = *(const float4*)&src[kbase + c * 4];
      *(float4*)&Vs[row * 68 + c * 4] = *(const float4*)&src[vbase + c * 4];
    }
    __syncthreads();

    #pragma unroll 1
    for (int ch = 0; ch < 4; ch++) {
      const int kb = ch * 16;
      float sc[16];
      // partial dots over this thread's 16-dim slice
      #pragma unroll
      for (int kk = 0; kk < 16; kk++) {
        const float* kp = &Ks[(kb + kk) * 68 + d0];
        float4 k0 = *(const float4*)(kp);
        float4 k1 = *(const float4*)(kp + 4);
        float4 k2 = *(const float4*)(kp + 8);
        float4 k3 = *(const float4*)(kp + 12);
        float s = Qr[0].x * k0.x + Qr[0].y * k0.y + Qr[0].z * k0.z + Qr[0].w * k0.w
                + Qr[1].x * k1.x + Qr[1].y * k1.y + Qr[1].z * k1.z + Qr[1].w * k1.w
                + Qr[2].x * k2.x + Qr[2].y * k2.y + Qr[2].z * k2.z + Qr[2].w * k2.w
                + Qr[3].x * k3.x + Qr[3].y * k3.y + Qr[3].z * k3.z + Qr[3].w * k3.w;
        sc[kk] = s;
      }
      // reduce across the 4-thread group (lanes q*4 .. q*4+3)
      #pragma unroll
      for (int kk = 0; kk < 16; kk++) {
        sc[kk] += __shfl_xor(sc[kk], 1, 64);
        sc[kk] += __shfl_xor(sc[kk], 2, 64);
      }
      // causal mask + chunk max
      float mx = m;
      #pragma unroll
      for (int kk = 0; kk < 16; kk++) {
        int kg = kt * 64 + kb + kk;
        if (kg > qg) sc[kk] = -3.0e38f;
        mx = fmaxf(mx, sc[kk]);
      }
      float mscale = (mx > -1.0e38f) ? __expf(m - mx) : 1.0f;
      float pi[16];
      float psum = 0.f;
      #pragma unroll
      for (int kk = 0; kk < 16; kk++) {
        int kg = kt * 64 + kb + kk;
        float p_ = (kg > qg) ? 0.f : __expf(sc[kk] - mx);
        pi[kk] = p_;
        psum += p_;
      }
      l = l * mscale + psum;
      m = mx;
      #pragma unroll
      for (int jj = 0; jj < 16; jj++) o[jj] *= mscale;
      // PV: accumulate this thread's 16-dim slice
      #pragma unroll
      for (int kk = 0; kk < 16; kk++) {
        const float* vp = &Vs[(kb + kk) * 68 + d0];
        float4 v0 = *(const float4*)(vp);
        float4 v1 = *(const float4*)(vp + 4);
        float4 v2 = *(const float4*)(vp + 8);
        float4 v3 = *(const float4*)(vp + 12);
        float p_ = pi[kk];
        o[0]  = fmaf(p_, v0.x, o[0]);  o[1]  = fmaf(p_, v0.y, o[1]);
        o[2]  = fmaf(p_, v0.z, o[2]);  o[3]  = fmaf(p_, v0.w, o[3]);
        o[4]  = fmaf(p_, v1.x, o[4]);  o[5]  = fmaf(p_, v1.y, o[5]);
        o[6]  = fmaf(p_, v1.z, o[6]);  o[7]  = fmaf(p_, v1.w, o[7]);
        o[8]  = fmaf(p_, v2.x, o[8]);  o[9]  = fmaf(p_, v2.y, o[9]);
        o[10] = fmaf(p_, v2.z, o[10]); o[11] = fmaf(p_, v2.w, o[11]);
        o[12] = fmaf(p_, v3.x, o[12]); o[13] = fmaf(p_, v3.y, o[13]);
        o[14] = fmaf(p_, v3.z, o[14]); o[15] = fmaf(p_, v3.w, o[15]);
      }
    }
    __syncthreads();
  }

  const float invl = 1.0f / l;   // diagonal always unmasked -> l > 0
  float* op = attn + qg * NQ + h * HDim + d0;
  #pragma unroll
  for (int jj = 0; jj < 16; jj++) op[jj] = o[jj] * invl;
}

// ---------------------------------------------------------------------------
// Kernel 3: output projection  attn [S][896] @ Wo [896][896] -> out
// ---------------------------------------------------------------------------
__global__ __launch_bounds__(256) void outproj_kernel(
    const float* __restrict__ attn, const float* __restrict__ Wo,
    float* __restrict__ out)
{
  __shared__ float hlds[Dm * 8];
  const int tid  = threadIdx.x;
  const int row0 = blockIdx.x * 8;

  for (int f = tid; f < 8 * Dm; f += 256) {
    int r = f / Dm;
    int d = f - r * Dm;
    hlds[d * 8 + r] = attn[(row0 + r) * Dm + d];
  }
  __syncthreads();

  float acc[4][8];
  bool valid[4];
  #pragma unroll
  for (int i = 0; i < 4; i++) {
    int n = tid + 256 * i;
    valid[i] = (n < NQ);
    #pragma unroll
    for (int r = 0; r < 8; r++) acc[i][r] = 0.f;
  }

  #pragma unroll 4
  for (int d = 0; d < Dm; d++) {
    float4 h0 = *(const float4*)&hlds[d * 8];
    float4 h1 = *(const float4*)&hlds[d * 8 + 4];
    float hv[8] = {h0.x, h0.y, h0.z, h0.w, h1.x, h1.y, h1.z, h1.w};
    #pragma unroll
    for (int i = 0; i < 4; i++) {
      int n = tid + 256 * i;
      float w = valid[i] ? Wo[d * NQ + n] : 0.f;
      #pragma unroll
      for (int r = 0; r < 8; r++) acc[i][r] = fmaf(hv[r], w, acc[i][r]);
    }
  }

  #pragma unroll
  for (int i = 0; i < 4; i++) {
    if (!valid[i]) continue;
    int n = tid + 256 * i;
    #pragma unroll
    for (int r = 0; r < 8; r++)
      out[(row0 + r) * NQ + n] = acc[i][r];
  }
}

// ---------------------------------------------------------------------------
extern "C" void kernel_launch(void* const* d_in, const int* in_sizes, int n_in,
                              void* d_out, int out_size, void* d_ws, size_t ws_size,
                              hipStream_t stream)
{
  const float* hs = (const float*)d_in[0];
  // d_in[1] = attention_mask (exactly causal; handled analytically)
  const float* Wq = (const float*)d_in[2];
  const float* bq = (const float*)d_in[3];
  const float* Wk = (const float*)d_in[4];
  const float* bk = (const float*)d_in[5];
  const float* Wv = (const float*)d_in[6];
  const float* bv = (const float*)d_in[7];
  const float* Wo = (const float*)d_in[8];

  float* qkv  = (float*)d_ws;                       // [4096][1152] f32
  float* attn = qkv + (size_t)S_ * NTOT;            // [4096][896]  f32
  float* out  = (float*)d_out;

  hipLaunchKernelGGL(qkv_rope_kernel, dim3(S_ / 8), dim3(256), 0, stream,
                     hs, Wq, bq, Wk, bk, Wv, bv, qkv);
  hipLaunchKernelGGL(flash_kernel, dim3(S_ / 64, NHd), dim3(256), 0, stream,
                     qkv, attn);
  hipLaunchKernelGGL(outproj_kernel, dim3(S_ / 8), dim3(256), 0, stream,
                     attn, Wo, out);
}

// Round 2
// 591.853 us; speedup vs baseline: 3.4812x; 3.4812x over previous
//
#include <hip/hip_runtime.h>
#include <hip/hip_bf16.h>
#include <math.h>

// Problem constants
constexpr int S_    = 4096;
constexpr int Dm    = 896;
constexpr int NHd   = 14;
constexpr int NKVh  = 2;
constexpr int HDim  = 64;
constexpr int NQ    = NHd * HDim;        // 896
constexpr int NK    = NKVh * HDim;       // 128
constexpr int NQK   = NQ + NK;           // 1024 (q+k buffer row stride)
constexpr int NTOT  = NQ + 2 * NK;       // 1152
constexpr int GROUPS = NHd / NKVh;       // 7
constexpr float L2B  = 19.9315685693241740873f;  // log2(1e6)

typedef __attribute__((ext_vector_type(8))) short bf16x8;
typedef __attribute__((ext_vector_type(4))) short bf16x4;
typedef __attribute__((ext_vector_type(4))) float f32x4;

__device__ inline short f2bf(float f) {            // RNE float->bf16
  unsigned u = __builtin_bit_cast(unsigned, f);
  unsigned r = (u + 0x7FFFu + ((u >> 16) & 1u)) >> 16;
  return (short)r;
}

// butterfly max over 16-lane groups via DPP (no LDS traffic)
#define DPPMAX(x, ctrl) \
  x = fmaxf(x, __builtin_bit_cast(float, __builtin_amdgcn_mov_dpp( \
      __builtin_bit_cast(int, (x)), (ctrl), 0xF, 0xF, 1)))
__device__ inline float red_max16(float x) {
  DPPMAX(x, 0xB1);   // quad_perm xor1
  DPPMAX(x, 0x4E);   // quad_perm xor2
  DPPMAX(x, 0x141);  // row_half_mirror (xor within 8)
  DPPMAX(x, 0x140);  // row_mirror (xor within 16)
  return x;
}

// ---------------------------------------------------------------------------
// Kernel 1: QKV GEMM + bias + RoPE. Writes qk [S][1024] f32 and vt [128][S] f32
// (V stored transposed so the flash kernel can stage V^T tiles coalesced).
// ---------------------------------------------------------------------------
__global__ __launch_bounds__(256) void qkv_rope_kernel(
    const float* __restrict__ hs,
    const float* __restrict__ Wq, const float* __restrict__ bq,
    const float* __restrict__ Wk, const float* __restrict__ bk,
    const float* __restrict__ Wv, const float* __restrict__ bv,
    float* __restrict__ qkbuf, float* __restrict__ vtbuf)
{
  __shared__ float hlds[Dm * 8];   // transposed: [d][r]
  const int tid  = threadIdx.x;
  const int row0 = blockIdx.x * 8;

  for (int f = tid; f < 8 * Dm; f += 256) {
    int r = f / Dm;
    int d = f - r * Dm;
    hlds[d * 8 + r] = hs[(row0 + r) * Dm + d];
  }
  __syncthreads();

  const float* wp[5];
  int wstride[5];
  bool valid[5];
  float acc[5][8];
  #pragma unroll
  for (int i = 0; i < 5; i++) {
    int n = tid + 256 * i;
    valid[i] = (n < NTOT);
    float b = 0.f;
    if (n < NQ)            { wp[i] = Wq + n;              wstride[i] = NQ; b = bq[n]; }
    else if (n < NQ + NK)  { wp[i] = Wk + (n - NQ);       wstride[i] = NK; b = bk[n - NQ]; }
    else if (n < NTOT)     { wp[i] = Wv + (n - NQ - NK);  wstride[i] = NK; b = bv[n - NQ - NK]; }
    else                   { wp[i] = Wv; wstride[i] = 0; }
    #pragma unroll
    for (int r = 0; r < 8; r++) acc[i][r] = b;
  }

  #pragma unroll 4
  for (int d = 0; d < Dm; d++) {
    float4 h0 = *(const float4*)&hlds[d * 8];
    float4 h1 = *(const float4*)&hlds[d * 8 + 4];
    float hv[8] = {h0.x, h0.y, h0.z, h0.w, h1.x, h1.y, h1.z, h1.w};
    #pragma unroll
    for (int i = 0; i < 5; i++) {
      float w = valid[i] ? wp[i][d * wstride[i]] : 0.f;
      #pragma unroll
      for (int r = 0; r < 8; r++) acc[i][r] = fmaf(hv[r], w, acc[i][r]);
    }
  }

  // RoPE on iterations 0..3 (columns < 1024 are exactly q and k)
  #pragma unroll
  for (int i = 0; i < 4; i++) {
    int n    = tid + 256 * i;
    int idim = n & 63;
    int j    = n & 31;
    float freq = exp2f(-(float)j * (L2B / 32.0f));
    float sgn  = (idim < 32) ? -1.f : 1.f;
    #pragma unroll
    for (int r = 0; r < 8; r++) {
      float partner = __shfl_xor(acc[i][r], 32, 64);
      float th = (float)(row0 + r) * freq;
      float sn, cs;
      sincosf(th, &sn, &cs);
      qkbuf[(size_t)(row0 + r) * NQK + n] = acc[i][r] * cs + sgn * partner * sn;
    }
  }
  // V -> transposed buffer vt[hd_col][s]
  {
    int n = tid + 1024;
    if (n < NTOT) {
      int vcol = n - 1024;
      float4 v0 = {acc[4][0], acc[4][1], acc[4][2], acc[4][3]};
      float4 v1 = {acc[4][4], acc[4][5], acc[4][6], acc[4][7]};
      *(float4*)(vtbuf + (size_t)vcol * S_ + row0)     = v0;
      *(float4*)(vtbuf + (size_t)vcol * S_ + row0 + 4) = v1;
    }
  }
}

// ---------------------------------------------------------------------------
// Kernel 2: MFMA flash attention (bf16 operands, f32 accum), causal.
// grid (32, 14) block 256 = 4 waves; wave handles 32 q-rows (2 m-tiles of 16).
// K LDS [64 key][64 hd] bf16, V^T LDS [64 hd][64 key] bf16, both row stride
// 128B with 16B-chunk XOR swizzle (chunk ^= row&7) for conflict-free b128.
// Row-sum l computed by MFMA against an all-ones B operand (same layout as O).
// ---------------------------------------------------------------------------
__global__ __launch_bounds__(256) void flash_mfma(
    const float* __restrict__ qk, const float* __restrict__ vt,
    float* __restrict__ attn)
{
  __shared__ char lds[32768];
  char* KsB = lds;             // 8 KB
  char* VtB = lds + 8192;      // 8 KB
  char* PsB = lds + 16384;     // 16 KB: per wave 2 m-tiles x [16][64] bf16

  const int tid  = threadIdx.x;
  const int lane = tid & 63;
  const int w    = tid >> 6;
  const int r16  = lane & 15;
  const int rg   = lane >> 4;
  const int h    = blockIdx.y;
  const int kv   = h / GROUPS;
  const int qt   = (int)gridDim.x - 1 - (int)blockIdx.x;  // big tiles first
  const int q0   = qt * 128;
  char* Pw = PsB + w * 4096;

  const int kbase = NQ + kv * HDim;

  // Q fragments (scaled by 1/sqrt(HD))
  bf16x8 aq[2][2];
  #pragma unroll
  for (int mt = 0; mt < 2; ++mt) {
    const float* qp = qk + (size_t)(q0 + w * 32 + mt * 16 + r16) * NQK + h * HDim + rg * 8;
    #pragma unroll
    for (int ks = 0; ks < 2; ++ks) {
      float4 f0 = *(const float4*)(qp + ks * 32);
      float4 f1 = *(const float4*)(qp + ks * 32 + 4);
      bf16x8 a;
      a[0] = f2bf(f0.x * 0.125f); a[1] = f2bf(f0.y * 0.125f);
      a[2] = f2bf(f0.z * 0.125f); a[3] = f2bf(f0.w * 0.125f);
      a[4] = f2bf(f1.x * 0.125f); a[5] = f2bf(f1.y * 0.125f);
      a[6] = f2bf(f1.z * 0.125f); a[7] = f2bf(f1.w * 0.125f);
      aq[mt][ks] = a;
    }
  }

  const f32x4 zero4 = {0.f, 0.f, 0.f, 0.f};
  f32x4 acc_o[2][4];
  f32x4 acc_l[2];
  float mrow[2][4];
  #pragma unroll
  for (int mt = 0; mt < 2; mt++) {
    acc_l[mt] = zero4;
    #pragma unroll
    for (int nt = 0; nt < 4; nt++) acc_o[mt][nt] = zero4;
    #pragma unroll
    for (int r = 0; r < 4; r++) mrow[mt][r] = -3.0e38f;
  }

  bf16x8 ones;
  #pragma unroll
  for (int j = 0; j < 8; j++) ones[j] = (short)0x3F80;  // bf16(1.0)

  const int nkt = 2 * qt + 2;
  for (int kt = 0; kt < nkt; ++kt) {
    __syncthreads();
    // stage K and V^T tiles as swizzled bf16
    #pragma unroll
    for (int p = 0; p < 4; ++p) {
      int idx = tid + 256 * p;
      int r   = idx >> 4;
      int c4  = (idx & 15) * 4;
      int dst = r * 128 + ((c4 * 2) ^ ((r & 7) << 4));
      float4 f = *(const float4*)(qk + (size_t)(kt * 64 + r) * NQK + kbase + c4);
      bf16x4 kp = { f2bf(f.x), f2bf(f.y), f2bf(f.z), f2bf(f.w) };
      *(bf16x4*)(KsB + dst) = kp;
      float4 g = *(const float4*)(vt + (size_t)(kv * 64 + r) * S_ + kt * 64 + c4);
      bf16x4 vp = { f2bf(g.x), f2bf(g.y), f2bf(g.z), f2bf(g.w) };
      *(bf16x4*)(VtB + dst) = vp;
    }
    __syncthreads();

    // S = Q K^T : sc[mt][nt] rows=(rg*4+r), cols=nt*16+r16
    f32x4 sc[2][4];
    #pragma unroll
    for (int mt = 0; mt < 2; mt++)
      #pragma unroll
      for (int nt = 0; nt < 4; nt++) sc[mt][nt] = zero4;

    #pragma unroll
    for (int nt = 0; nt < 4; ++nt) {
      int key = nt * 16 + r16;
      #pragma unroll
      for (int ks = 0; ks < 2; ++ks) {
        bf16x8 bk = *(const bf16x8*)(KsB + key * 128 + (((rg + 4 * ks) ^ (lane & 7)) << 4));
        sc[0][nt] = __builtin_amdgcn_mfma_f32_16x16x32_bf16(aq[0][ks], bk, sc[0][nt], 0, 0, 0);
        sc[1][nt] = __builtin_amdgcn_mfma_f32_16x16x32_bf16(aq[1][ks], bk, sc[1][nt], 0, 0, 0);
      }
    }

    // online softmax; write P (bf16) to wave-private swizzled LDS
    #pragma unroll
    for (int mt = 0; mt < 2; ++mt) {
      const int tilebase = q0 + w * 32 + mt * 16;
      const bool domask = (kt * 64 + 63) > tilebase;
      float pexp[4][4];
      #pragma unroll
      for (int r = 0; r < 4; ++r) {
        int qg = tilebase + rg * 4 + r;
        float s0 = sc[mt][0][r], s1 = sc[mt][1][r], s2 = sc[mt][2][r], s3 = sc[mt][3][r];
        if (domask) {
          int kg = kt * 64 + r16;
          s0 = (kg      > qg) ? -3.0e38f : s0;
          s1 = (kg + 16 > qg) ? -3.0e38f : s1;
          s2 = (kg + 32 > qg) ? -3.0e38f : s2;
          s3 = (kg + 48 > qg) ? -3.0e38f : s3;
        }
        float mx = red_max16(fmaxf(fmaxf(s0, s1), fmaxf(s2, s3)));
        float newm = fmaxf(mrow[mt][r], mx);
        float scl = __expf(mrow[mt][r] - newm);
        mrow[mt][r] = newm;
        pexp[0][r] = __expf(s0 - newm);
        pexp[1][r] = __expf(s1 - newm);
        pexp[2][r] = __expf(s2 - newm);
        pexp[3][r] = __expf(s3 - newm);
        acc_l[mt][r] *= scl;
        #pragma unroll
        for (int nt = 0; nt < 4; nt++) acc_o[mt][nt][r] *= scl;
      }
      #pragma unroll
      for (int nt = 0; nt < 4; nt++)
        #pragma unroll
        for (int r = 0; r < 4; r++) {
          int prow = rg * 4 + r;
          int col2 = (nt * 16 + r16) * 2;
          *(short*)(Pw + mt * 2048 + prow * 128 + (col2 ^ ((prow & 7) << 4))) =
              f2bf(pexp[nt][r]);
        }
    }

    // O += P V ; l += P . 1   (DS ops are in-order within a wave: no barrier)
    #pragma unroll
    for (int ks = 0; ks < 2; ++ks) {
      int ch = ((rg + 4 * ks) ^ (lane & 7)) << 4;
      bf16x8 ap0 = *(const bf16x8*)(Pw +        r16 * 128 + ch);
      bf16x8 ap1 = *(const bf16x8*)(Pw + 2048 + r16 * 128 + ch);
      acc_l[0] = __builtin_amdgcn_mfma_f32_16x16x32_bf16(ap0, ones, acc_l[0], 0, 0, 0);
      acc_l[1] = __builtin_amdgcn_mfma_f32_16x16x32_bf16(ap1, ones, acc_l[1], 0, 0, 0);
      #pragma unroll
      for (int nt = 0; nt < 4; ++nt) {
        int hd = nt * 16 + r16;
        bf16x8 bv = *(const bf16x8*)(VtB + hd * 128 + (((rg + 4 * ks) ^ (lane & 7)) << 4));
        acc_o[0][nt] = __builtin_amdgcn_mfma_f32_16x16x32_bf16(ap0, bv, acc_o[0][nt], 0, 0, 0);
        acc_o[1][nt] = __builtin_amdgcn_mfma_f32_16x16x32_bf16(ap1, bv, acc_o[1][nt], 0, 0, 0);
      }
    }
  }

  // epilogue: normalize by l (replicated across the 16 lanes -> no shuffles)
  #pragma unroll
  for (int mt = 0; mt < 2; mt++)
    #pragma unroll
    for (int r = 0; r < 4; r++) {
      float inv = 1.0f / acc_l[mt][r];
      int qg = q0 + w * 32 + mt * 16 + rg * 4 + r;
      float* op = attn + (size_t)qg * NQ + h * HDim + r16;
      #pragma unroll
      for (int nt = 0; nt < 4; nt++) op[nt * 16] = acc_o[mt][nt][r] * inv;
    }
}

// ---------------------------------------------------------------------------
// Kernel 3: output projection  attn [S][896] @ Wo [896][896] -> out
// ---------------------------------------------------------------------------
__global__ __launch_bounds__(256) void outproj_kernel(
    const float* __restrict__ attn, const float* __restrict__ Wo,
    float* __restrict__ out)
{
  __shared__ float hlds[Dm * 8];
  const int tid  = threadIdx.x;
  const int row0 = blockIdx.x * 8;

  for (int f = tid; f < 8 * Dm; f += 256) {
    int r = f / Dm;
    int d = f - r * Dm;
    hlds[d * 8 + r] = attn[(row0 + r) * Dm + d];
  }
  __syncthreads();

  float acc[4][8];
  bool valid[4];
  #pragma unroll
  for (int i = 0; i < 4; i++) {
    int n = tid + 256 * i;
    valid[i] = (n < NQ);
    #pragma unroll
    for (int r = 0; r < 8; r++) acc[i][r] = 0.f;
  }

  #pragma unroll 4
  for (int d = 0; d < Dm; d++) {
    float4 h0 = *(const float4*)&hlds[d * 8];
    float4 h1 = *(const float4*)&hlds[d * 8 + 4];
    float hv[8] = {h0.x, h0.y, h0.z, h0.w, h1.x, h1.y, h1.z, h1.w};
    #pragma unroll
    for (int i = 0; i < 4; i++) {
      int n = tid + 256 * i;
      float w = valid[i] ? Wo[d * NQ + n] : 0.f;
      #pragma unroll
      for (int r = 0; r < 8; r++) acc[i][r] = fmaf(hv[r], w, acc[i][r]);
    }
  }

  #pragma unroll
  for (int i = 0; i < 4; i++) {
    if (!valid[i]) continue;
    int n = tid + 256 * i;
    #pragma unroll
    for (int r = 0; r < 8; r++)
      out[(row0 + r) * NQ + n] = acc[i][r];
  }
}

// ---------------------------------------------------------------------------
extern "C" void kernel_launch(void* const* d_in, const int* in_sizes, int n_in,
                              void* d_out, int out_size, void* d_ws, size_t ws_size,
                              hipStream_t stream)
{
  const float* hs = (const float*)d_in[0];
  // d_in[1] = attention_mask (exactly causal; handled analytically)
  const float* Wq = (const float*)d_in[2];
  const float* bq = (const float*)d_in[3];
  const float* Wk = (const float*)d_in[4];
  const float* bk = (const float*)d_in[5];
  const float* Wv = (const float*)d_in[6];
  const float* bv = (const float*)d_in[7];
  const float* Wo = (const float*)d_in[8];

  float* qkb  = (float*)d_ws;                     // [4096][1024] f32 (q|k, roped)
  float* vtb  = qkb + (size_t)S_ * NQK;           // [128][4096]  f32 (V^T)
  float* attn = vtb + (size_t)NK * S_;            // [4096][896]  f32
  float* out  = (float*)d_out;

  hipLaunchKernelGGL(qkv_rope_kernel, dim3(S_ / 8), dim3(256), 0, stream,
                     hs, Wq, bq, Wk, bk, Wv, bv, qkb, vtb);
  hipLaunchKernelGGL(flash_mfma, dim3(S_ / 128, NHd), dim3(256), 0, stream,
                     qkb, vtb, attn);
  hipLaunchKernelGGL(outproj_kernel, dim3(S_ / 8), dim3(256), 0, stream,
                     attn, Wo, out);
}

// Round 3
// 210.360 us; speedup vs baseline: 9.7946x; 2.8135x over previous
//
#include <hip/hip_runtime.h>
#include <math.h>

// Problem constants
constexpr int S_    = 4096;
constexpr int Dm    = 896;
constexpr int NHd   = 14;
constexpr int NKVh  = 2;
constexpr int HDim  = 64;
constexpr int NQ    = NHd * HDim;        // 896
constexpr int NK    = NKVh * HDim;       // 128
constexpr int NQK   = NQ + NK;           // 1024 (qk buffer row stride)
constexpr int GROUPS = NHd / NKVh;       // 7
constexpr float L2B  = 19.9315685693241740873f;  // log2(1e6)

typedef __attribute__((ext_vector_type(8))) short bf16x8;
typedef __attribute__((ext_vector_type(4))) short bf16x4;
typedef __attribute__((ext_vector_type(4))) float f32x4;

__device__ __forceinline__ short f2bf(float f) {   // RNE float->bf16
  unsigned u = __builtin_bit_cast(unsigned, f);
  unsigned r = (u + 0x7FFFu + ((u >> 16) & 1u)) >> 16;
  return (short)r;
}

// async global->LDS, 16 bytes per lane; lds dest is wave-uniform base + lane*16
__device__ __forceinline__ void gload16(const void* g, void* l) {
  __builtin_amdgcn_global_load_lds(
      (const __attribute__((address_space(1))) unsigned int*)g,
      (__attribute__((address_space(3))) unsigned int*)l, 16, 0, 0);
}

// butterfly max over 16-lane groups via DPP
#define DPPMAX(x, ctrl) \
  x = fmaxf(x, __builtin_bit_cast(float, __builtin_amdgcn_mov_dpp( \
      __builtin_bit_cast(int, (x)), (ctrl), 0xF, 0xF, 1)))
__device__ __forceinline__ float red_max16(float x) {
  DPPMAX(x, 0xB1);   // quad_perm xor1
  DPPMAX(x, 0x4E);   // quad_perm xor2
  DPPMAX(x, 0x141);  // row_half_mirror
  DPPMAX(x, 0x140);  // row_mirror
  return x;
}

// ---------------------------------------------------------------------------
// Prep: convert hidden_states f32 -> bf16 (row-major [4096][896])
// ---------------------------------------------------------------------------
__global__ __launch_bounds__(256) void cvt_hs(const float* __restrict__ src,
                                              short* __restrict__ dst)
{
  int idx = blockIdx.x * 256 + threadIdx.x;       // one per 8 elements
  float4 a = ((const float4*)src)[idx * 2];
  float4 b = ((const float4*)src)[idx * 2 + 1];
  bf16x8 o;
  o[0] = f2bf(a.x); o[1] = f2bf(a.y); o[2] = f2bf(a.z); o[3] = f2bf(a.w);
  o[4] = f2bf(b.x); o[5] = f2bf(b.y); o[6] = f2bf(b.z); o[7] = f2bf(b.w);
  ((bf16x8*)dst)[idx] = o;
}

// ---------------------------------------------------------------------------
// Prep: RoPE tables cos/sin [4096][32] f32
// ---------------------------------------------------------------------------
__global__ __launch_bounds__(256) void rope_tab(float* __restrict__ cost,
                                                float* __restrict__ sint)
{
  int idx = blockIdx.x * 256 + threadIdx.x;       // m*32 + j
  int m = idx >> 5, j = idx & 31;
  float invf = exp2f(-(float)j * (L2B / 32.0f));
  float th = (float)m * invf;
  float s, c;
  sincosf(th, &s, &c);
  cost[idx] = c;
  sint[idx] = s;
}

// ---------------------------------------------------------------------------
// Prep: transpose W [896][srcN] f32 -> dst rows [srcN][896] bf16 (at rowOff)
// grid (896/64, srcN/64), block 256
// ---------------------------------------------------------------------------
__global__ __launch_bounds__(256) void transpose_w(
    const float* __restrict__ src, int srcN,
    short* __restrict__ dst, int rowOff)
{
  __shared__ float t[64 * 68];
  const int kt = blockIdx.x, nt = blockIdx.y;
  const int tid = threadIdx.x;
  #pragma unroll
  for (int i = 0; i < 4; i++) {
    int idx = tid + i * 256;
    int r = idx >> 4, c4 = (idx & 15) * 4;
    *(float4*)&t[r * 68 + c4] =
        *(const float4*)&src[(size_t)(kt * 64 + r) * srcN + nt * 64 + c4];
  }
  __syncthreads();
  const int nl = tid >> 2;
  const int kc = (tid & 3) * 16;
  bf16x8 o0, o1;
  #pragma unroll
  for (int i = 0; i < 8; i++) o0[i] = f2bf(t[(kc + i) * 68 + nl]);
  #pragma unroll
  for (int i = 0; i < 8; i++) o1[i] = f2bf(t[(kc + 8 + i) * 68 + nl]);
  short* dp = dst + (size_t)(rowOff + nt * 64 + nl) * 896 + kt * 64 + kc;
  *(bf16x8*)dp = o0;
  *(bf16x8*)(dp + 8) = o1;
}

// ---------------------------------------------------------------------------
// MFMA GEMM, 128x128 tile, BK=64, 4 waves (2x2), m97 structure.
// A [4096][896] bf16, Bt [N][896] bf16 (pre-transposed weights).
// EPI==0: QKV epilogue (bias + RoPE + Q*0.125; writes qkb bf16 and vtb bf16^T)
// EPI==1: plain f32 store to outp [4096][896]
// ---------------------------------------------------------------------------
template<int EPI>
__global__ __launch_bounds__(256) void gemm128(
    const short* __restrict__ A, const short* __restrict__ Bt,
    const float* __restrict__ biasq, const float* __restrict__ biask,
    const float* __restrict__ biasv,
    const float* __restrict__ cost, const float* __restrict__ sint,
    short* __restrict__ qkb, short* __restrict__ vtb,
    float* __restrict__ outp)
{
  __shared__ short Als[128 * 64];
  __shared__ short Bls[128 * 64];
  const int tid = threadIdx.x;
  const int lane = tid & 63;
  const int w = tid >> 6;
  const int wm = w >> 1, wn = w & 1;
  const int r16 = lane & 15, rg = lane >> 4;
  const int bm = blockIdx.x, bn = blockIdx.y;

  const f32x4 zero4 = {0.f, 0.f, 0.f, 0.f};
  f32x4 acc[4][4];
  #pragma unroll
  for (int mt = 0; mt < 4; mt++)
    #pragma unroll
    for (int nt = 0; nt < 4; nt++) acc[mt][nt] = zero4;

  const int srow = (lane >> 3);
  const int scol = (lane & 7) * 8;

  for (int kt = 0; kt < 14; ++kt) {
    __syncthreads();   // previous tile fully consumed
    #pragma unroll
    for (int i = 0; i < 4; i++) {
      int c = i * 4 + w;
      int row = c * 8 + srow;
      gload16(A  + (size_t)(bm * 128 + row) * 896 + kt * 64 + scol, &Als[c * 512]);
      gload16(Bt + (size_t)(bn * 128 + row) * 896 + kt * 64 + scol, &Bls[c * 512]);
    }
    __syncthreads();   // compiler drains vmcnt before barrier

    bf16x8 af[4][2], bf[4][2];
    #pragma unroll
    for (int mt = 0; mt < 4; mt++)
      #pragma unroll
      for (int ks = 0; ks < 2; ks++)
        af[mt][ks] = *(const bf16x8*)&Als[(wm * 64 + mt * 16 + r16) * 64 + ks * 32 + rg * 8];
    #pragma unroll
    for (int nt = 0; nt < 4; nt++)
      #pragma unroll
      for (int ks = 0; ks < 2; ks++)
        bf[nt][ks] = *(const bf16x8*)&Bls[(wn * 64 + nt * 16 + r16) * 64 + ks * 32 + rg * 8];
    #pragma unroll
    for (int mt = 0; mt < 4; mt++)
      #pragma unroll
      for (int nt = 0; nt < 4; nt++)
        #pragma unroll
        for (int ks = 0; ks < 2; ks++)
          acc[mt][nt] = __builtin_amdgcn_mfma_f32_16x16x32_bf16(
              af[mt][ks], bf[nt][ks], acc[mt][nt], 0, 0, 0);
  }

  if (EPI == 0) {
    const int nbase = bn * 128 + wn * 64;
    if (bn < 8) {
      // q (bn<7, scaled 1/8) or k (bn==7) with bias + RoPE
      const float scl = (bn < 7) ? 0.125f : 1.0f;
      const float* bias = (bn < 7) ? biasq : (biask - 896);
      #pragma unroll
      for (int mt = 0; mt < 4; mt++) {
        const int m0 = bm * 128 + wm * 64 + mt * 16 + rg * 4;
        #pragma unroll
        for (int nt = 0; nt < 4; nt++) {
          int n = nbase + nt * 16 + r16;
          int j = n & 31;
          float sgn = (n & 32) ? 1.f : -1.f;
          float b0 = bias[n], b1 = bias[n ^ 32];
          #pragma unroll
          for (int r = 0; r < 4; r++) {
            int m = m0 + r;
            float c_ = cost[m * 32 + j], s_ = sint[m * 32 + j];
            float val = ((acc[mt][nt][r] + b0) * c_ +
                         sgn * (acc[mt][nt ^ 2][r] + b1) * s_) * scl;
            qkb[(size_t)m * NQK + n] = f2bf(val);
          }
        }
      }
    } else {
      // v -> vtb [128][4096] transposed
      #pragma unroll
      for (int mt = 0; mt < 4; mt++) {
        const int m0 = bm * 128 + wm * 64 + mt * 16 + rg * 4;
        #pragma unroll
        for (int nt = 0; nt < 4; nt++) {
          int vc = wn * 64 + nt * 16 + r16;   // 0..127
          float b0 = biasv[vc];
          bf16x4 pk;
          #pragma unroll
          for (int r = 0; r < 4; r++) pk[r] = f2bf(acc[mt][nt][r] + b0);
          *(bf16x4*)&vtb[(size_t)vc * S_ + m0] = pk;
        }
      }
    }
  } else {
    #pragma unroll
    for (int mt = 0; mt < 4; mt++) {
      const int m0 = bm * 128 + wm * 64 + mt * 16 + rg * 4;
      #pragma unroll
      for (int nt = 0; nt < 4; nt++) {
        int n = bn * 128 + wn * 64 + nt * 16 + r16;
        #pragma unroll
        for (int r = 0; r < 4; r++)
          outp[(size_t)(m0 + r) * NQ + n] = acc[mt][nt][r];
      }
    }
  }
}

// ---------------------------------------------------------------------------
// Flash attention: bf16 in (qkb, vtb), bf16 out (attnb). 8 waves x 16 q-rows,
// QBLK=128, KBLK=64. K and V^T LDS XOR-swizzled for conflict-free b128 reads.
// ---------------------------------------------------------------------------
__global__ __launch_bounds__(512) void flash_mfma(
    const short* __restrict__ qkb, const short* __restrict__ vtb,
    short* __restrict__ attnb)
{
  __shared__ char lds[32768];
  char* KsB = lds;             // 8 KB
  char* VtB = lds + 8192;      // 8 KB
  char* PsB = lds + 16384;     // 16 KB = 8 waves x 2 KB

  const int tid  = threadIdx.x;
  const int lane = tid & 63;
  const int w    = tid >> 6;
  const int r16  = lane & 15;
  const int rg   = lane >> 4;
  const int h    = blockIdx.y;
  const int kv   = h / GROUPS;
  const int qt   = (int)gridDim.x - 1 - (int)blockIdx.x;  // big tiles first
  const int q0   = qt * 128;
  char* Pw = PsB + w * 2048;
  const int kbase = NQ + kv * HDim;

  // Q fragments (already scaled by 1/8 at GEMM epilogue)
  bf16x8 aq[2];
  {
    const short* qp = qkb + (size_t)(q0 + w * 16 + r16) * NQK + h * HDim + rg * 8;
    aq[0] = *(const bf16x8*)qp;
    aq[1] = *(const bf16x8*)(qp + 32);
  }

  const f32x4 zero4 = {0.f, 0.f, 0.f, 0.f};
  f32x4 acc_o[4];
  f32x4 acc_l = zero4;
  float mrow[4];
  #pragma unroll
  for (int nt = 0; nt < 4; nt++) acc_o[nt] = zero4;
  #pragma unroll
  for (int r = 0; r < 4; r++) mrow[r] = -3.0e38f;

  bf16x8 ones;
  #pragma unroll
  for (int j = 0; j < 8; j++) ones[j] = (short)0x3F80;  // bf16(1.0)

  const int nkt = 2 * qt + 2;
  for (int kt = 0; kt < nkt; ++kt) {
    __syncthreads();
    {
      int row = tid >> 3, c8 = tid & 7;
      int dst = row * 128 + ((c8 * 16) ^ ((row & 7) << 4));
      *(bf16x8*)(KsB + dst) =
          *(const bf16x8*)(qkb + (size_t)(kt * 64 + row) * NQK + kbase + c8 * 8);
      *(bf16x8*)(VtB + dst) =
          *(const bf16x8*)(vtb + (size_t)(kv * HDim + row) * S_ + kt * 64 + c8 * 8);
    }
    __syncthreads();

    // S = Q K^T
    f32x4 sc[4];
    #pragma unroll
    for (int nt = 0; nt < 4; nt++) sc[nt] = zero4;
    #pragma unroll
    for (int nt = 0; nt < 4; ++nt) {
      int key = nt * 16 + r16;
      #pragma unroll
      for (int ks = 0; ks < 2; ++ks) {
        bf16x8 bk = *(const bf16x8*)(KsB + key * 128 + (((rg + 4 * ks) ^ (lane & 7)) << 4));
        sc[nt] = __builtin_amdgcn_mfma_f32_16x16x32_bf16(aq[ks], bk, sc[nt], 0, 0, 0);
      }
    }

    // online softmax
    const int tilebase = q0 + w * 16;
    const bool domask = (kt * 64 + 63) > tilebase;
    float pexp[4][4];
    #pragma unroll
    for (int r = 0; r < 4; ++r) {
      int qg = tilebase + rg * 4 + r;
      float s0 = sc[0][r], s1 = sc[1][r], s2 = sc[2][r], s3 = sc[3][r];
      if (domask) {
        int kg = kt * 64 + r16;
        s0 = (kg      > qg) ? -3.0e38f : s0;
        s1 = (kg + 16 > qg) ? -3.0e38f : s1;
        s2 = (kg + 32 > qg) ? -3.0e38f : s2;
        s3 = (kg + 48 > qg) ? -3.0e38f : s3;
      }
      float mx = red_max16(fmaxf(fmaxf(s0, s1), fmaxf(s2, s3)));
      float newm = fmaxf(mrow[r], mx);
      float scl = __expf(mrow[r] - newm);
      mrow[r] = newm;
      pexp[0][r] = __expf(s0 - newm);
      pexp[1][r] = __expf(s1 - newm);
      pexp[2][r] = __expf(s2 - newm);
      pexp[3][r] = __expf(s3 - newm);
      acc_l[r] *= scl;
      #pragma unroll
      for (int nt = 0; nt < 4; nt++) acc_o[nt][r] *= scl;
    }
    #pragma unroll
    for (int nt = 0; nt < 4; nt++)
      #pragma unroll
      for (int r = 0; r < 4; r++) {
        int prow = rg * 4 + r;
        int col2 = (nt * 16 + r16) * 2;
        *(short*)(Pw + prow * 128 + (col2 ^ ((prow & 7) << 4))) = f2bf(pexp[nt][r]);
      }

    // O += P V ; l += P . 1   (wave-private P region; DS in-order, no barrier)
    #pragma unroll
    for (int ks = 0; ks < 2; ++ks) {
      int ch = ((rg + 4 * ks) ^ (lane & 7)) << 4;
      bf16x8 ap = *(const bf16x8*)(Pw + r16 * 128 + ch);
      acc_l = __builtin_amdgcn_mfma_f32_16x16x32_bf16(ap, ones, acc_l, 0, 0, 0);
      #pragma unroll
      for (int nt = 0; nt < 4; ++nt) {
        int hd = nt * 16 + r16;
        bf16x8 bv = *(const bf16x8*)(VtB + hd * 128 + (((rg + 4 * ks) ^ (lane & 7)) << 4));
        acc_o[nt] = __builtin_amdgcn_mfma_f32_16x16x32_bf16(ap, bv, acc_o[nt], 0, 0, 0);
      }
    }
  }

  // epilogue: normalize, write bf16
  #pragma unroll
  for (int r = 0; r < 4; r++) {
    float inv = 1.0f / acc_l[r];
    int qg = q0 + w * 16 + rg * 4 + r;
    short* op = attnb + (size_t)qg * NQ + h * HDim + r16;
    #pragma unroll
    for (int nt = 0; nt < 4; nt++) op[nt * 16] = f2bf(acc_o[nt][r] * inv);
  }
}

// ---------------------------------------------------------------------------
extern "C" void kernel_launch(void* const* d_in, const int* in_sizes, int n_in,
                              void* d_out, int out_size, void* d_ws, size_t ws_size,
                              hipStream_t stream)
{
  const float* hs = (const float*)d_in[0];
  // d_in[1] = attention_mask (exactly causal; handled analytically)
  const float* Wq = (const float*)d_in[2];
  const float* bq = (const float*)d_in[3];
  const float* Wk = (const float*)d_in[4];
  const float* bk = (const float*)d_in[5];
  const float* Wv = (const float*)d_in[6];
  const float* bv = (const float*)d_in[7];
  const float* Wo = (const float*)d_in[8];

  short* hsb  = (short*)d_ws;                     // [4096][896]  bf16
  short* wtq  = hsb + (size_t)S_ * Dm;            // [1152][896]  bf16 (Wq|Wk|Wv ^T)
  short* wto  = wtq + (size_t)1152 * 896;         // [896][896]   bf16 (Wo^T)
  float* cost = (float*)(wto + (size_t)896 * 896);// [4096][32]   f32
  float* sint = cost + (size_t)S_ * 32;           // [4096][32]   f32
  short* qkb  = (short*)(sint + (size_t)S_ * 32); // [4096][1024] bf16 (q*0.125|k, roped)
  short* vtb  = qkb + (size_t)S_ * NQK;           // [128][4096]  bf16 (V^T)
  short* attnb= vtb + (size_t)NK * S_;            // [4096][896]  bf16
  float* out  = (float*)d_out;

  hipLaunchKernelGGL(cvt_hs,   dim3(S_ * Dm / 8 / 256), dim3(256), 0, stream, hs, hsb);
  hipLaunchKernelGGL(rope_tab, dim3(S_ * 32 / 256),     dim3(256), 0, stream, cost, sint);
  hipLaunchKernelGGL(transpose_w, dim3(14, 14), dim3(256), 0, stream, Wq, NQ, wtq, 0);
  hipLaunchKernelGGL(transpose_w, dim3(14, 2),  dim3(256), 0, stream, Wk, NK, wtq, 896);
  hipLaunchKernelGGL(transpose_w, dim3(14, 2),  dim3(256), 0, stream, Wv, NK, wtq, 1024);
  hipLaunchKernelGGL(transpose_w, dim3(14, 14), dim3(256), 0, stream, Wo, NQ, wto, 0);

  hipLaunchKernelGGL((gemm128<0>), dim3(32, 9), dim3(256), 0, stream,
                     hsb, wtq, bq, bk, bv, cost, sint, qkb, vtb, (float*)nullptr);
  hipLaunchKernelGGL(flash_mfma, dim3(S_ / 128, NHd), dim3(512), 0, stream,
                     qkb, vtb, attnb);
  hipLaunchKernelGGL((gemm128<1>), dim3(32, 7), dim3(256), 0, stream,
                     attnb, wto, bq, bk, bv, cost, sint,
                     (short*)nullptr, (short*)nullptr, out);
}

// Round 4
// 184.339 us; speedup vs baseline: 11.1771x; 1.1412x over previous
//
#include <hip/hip_runtime.h>
#include <math.h>

// Problem constants
constexpr int S_    = 4096;
constexpr int Dm    = 896;
constexpr int NHd   = 14;
constexpr int NKVh  = 2;
constexpr int HDim  = 64;
constexpr int NQ    = NHd * HDim;        // 896
constexpr int NK    = NKVh * HDim;       // 128
constexpr int NQK   = NQ + NK;           // 1024 (qk buffer row stride)
constexpr int GROUPS = NHd / NKVh;       // 7
constexpr float L2B   = 19.9315685693241740873f;  // log2(1e6)
constexpr float LOG2E = 1.44269504088896340736f;

typedef __attribute__((ext_vector_type(8))) short bf16x8;
typedef __attribute__((ext_vector_type(4))) short bf16x4;
typedef __attribute__((ext_vector_type(4))) float f32x4;

__device__ __forceinline__ short f2bf(float f) {   // RNE float->bf16
  unsigned u = __builtin_bit_cast(unsigned, f);
  unsigned r = (u + 0x7FFFu + ((u >> 16) & 1u)) >> 16;
  return (short)r;
}

// async global->LDS, 16 bytes per lane; lds dest is wave-uniform base + lane*16
__device__ __forceinline__ void gload16(const void* g, void* l) {
  __builtin_amdgcn_global_load_lds(
      (const __attribute__((address_space(1))) unsigned int*)g,
      (__attribute__((address_space(3))) unsigned int*)l, 16, 0, 0);
}

// butterfly max over 16-lane groups via DPP
#define DPPMAX(x, ctrl) \
  x = fmaxf(x, __builtin_bit_cast(float, __builtin_amdgcn_mov_dpp( \
      __builtin_bit_cast(int, (x)), (ctrl), 0xF, 0xF, 1)))
__device__ __forceinline__ float red_max16(float x) {
  DPPMAX(x, 0xB1);   // quad_perm xor1
  DPPMAX(x, 0x4E);   // quad_perm xor2
  DPPMAX(x, 0x141);  // row_half_mirror
  DPPMAX(x, 0x140);  // row_mirror
  return x;
}

// ---------------------------------------------------------------------------
// Prep: convert hidden_states f32 -> bf16
// ---------------------------------------------------------------------------
__global__ __launch_bounds__(256) void cvt_hs(const float* __restrict__ src,
                                              short* __restrict__ dst)
{
  int idx = blockIdx.x * 256 + threadIdx.x;
  float4 a = ((const float4*)src)[idx * 2];
  float4 b = ((const float4*)src)[idx * 2 + 1];
  bf16x8 o;
  o[0] = f2bf(a.x); o[1] = f2bf(a.y); o[2] = f2bf(a.z); o[3] = f2bf(a.w);
  o[4] = f2bf(b.x); o[5] = f2bf(b.y); o[6] = f2bf(b.z); o[7] = f2bf(b.w);
  ((bf16x8*)dst)[idx] = o;
}

// ---------------------------------------------------------------------------
// Prep: RoPE tables cos/sin [4096][32] f32
// ---------------------------------------------------------------------------
__global__ __launch_bounds__(256) void rope_tab(float* __restrict__ cost,
                                                float* __restrict__ sint)
{
  int idx = blockIdx.x * 256 + threadIdx.x;
  int m = idx >> 5, j = idx & 31;
  float invf = exp2f(-(float)j * (L2B / 32.0f));
  float th = (float)m * invf;
  float s, c;
  sincosf(th, &s, &c);
  cost[idx] = c;
  sint[idx] = s;
}

// ---------------------------------------------------------------------------
// Prep: transpose W [896][srcN] f32 -> dst rows [srcN][896] bf16 (at rowOff)
// ---------------------------------------------------------------------------
__global__ __launch_bounds__(256) void transpose_w(
    const float* __restrict__ src, int srcN,
    short* __restrict__ dst, int rowOff)
{
  __shared__ float t[64 * 68];
  const int kt = blockIdx.x, nt = blockIdx.y;
  const int tid = threadIdx.x;
  #pragma unroll
  for (int i = 0; i < 4; i++) {
    int idx = tid + i * 256;
    int r = idx >> 4, c4 = (idx & 15) * 4;
    *(float4*)&t[r * 68 + c4] =
        *(const float4*)&src[(size_t)(kt * 64 + r) * srcN + nt * 64 + c4];
  }
  __syncthreads();
  const int nl = tid >> 2;
  const int kc = (tid & 3) * 16;
  bf16x8 o0, o1;
  #pragma unroll
  for (int i = 0; i < 8; i++) o0[i] = f2bf(t[(kc + i) * 68 + nl]);
  #pragma unroll
  for (int i = 0; i < 8; i++) o1[i] = f2bf(t[(kc + 8 + i) * 68 + nl]);
  short* dp = dst + (size_t)(rowOff + nt * 64 + nl) * 896 + kt * 64 + kc;
  *(bf16x8*)dp = o0;
  *(bf16x8*)(dp + 8) = o1;
}

// ---------------------------------------------------------------------------
// MFMA GEMM, 128x128 tile, BK=64, 4 waves (2x2), m97 structure.
// EPI==0: QKV epilogue (bias + RoPE; Q scaled by log2e/8 for exp2 softmax;
//         writes qkb bf16 and vtb bf16 transposed)
// EPI==1: plain f32 store
// ---------------------------------------------------------------------------
template<int EPI>
__global__ __launch_bounds__(256) void gemm128(
    const short* __restrict__ A, const short* __restrict__ Bt,
    const float* __restrict__ biasq, const float* __restrict__ biask,
    const float* __restrict__ biasv,
    const float* __restrict__ cost, const float* __restrict__ sint,
    short* __restrict__ qkb, short* __restrict__ vtb,
    float* __restrict__ outp)
{
  __shared__ short Als[128 * 64];
  __shared__ short Bls[128 * 64];
  const int tid = threadIdx.x;
  const int lane = tid & 63;
  const int w = tid >> 6;
  const int wm = w >> 1, wn = w & 1;
  const int r16 = lane & 15, rg = lane >> 4;
  const int bm = blockIdx.x, bn = blockIdx.y;

  const f32x4 zero4 = {0.f, 0.f, 0.f, 0.f};
  f32x4 acc[4][4];
  #pragma unroll
  for (int mt = 0; mt < 4; mt++)
    #pragma unroll
    for (int nt = 0; nt < 4; nt++) acc[mt][nt] = zero4;

  const int srow = (lane >> 3);
  const int scol = (lane & 7) * 8;

  for (int kt = 0; kt < 14; ++kt) {
    __syncthreads();
    #pragma unroll
    for (int i = 0; i < 4; i++) {
      int c = i * 4 + w;
      int row = c * 8 + srow;
      gload16(A  + (size_t)(bm * 128 + row) * 896 + kt * 64 + scol, &Als[c * 512]);
      gload16(Bt + (size_t)(bn * 128 + row) * 896 + kt * 64 + scol, &Bls[c * 512]);
    }
    __syncthreads();

    bf16x8 af[4][2], bf[4][2];
    #pragma unroll
    for (int mt = 0; mt < 4; mt++)
      #pragma unroll
      for (int ks = 0; ks < 2; ks++)
        af[mt][ks] = *(const bf16x8*)&Als[(wm * 64 + mt * 16 + r16) * 64 + ks * 32 + rg * 8];
    #pragma unroll
    for (int nt = 0; nt < 4; nt++)
      #pragma unroll
      for (int ks = 0; ks < 2; ks++)
        bf[nt][ks] = *(const bf16x8*)&Bls[(wn * 64 + nt * 16 + r16) * 64 + ks * 32 + rg * 8];
    #pragma unroll
    for (int mt = 0; mt < 4; mt++)
      #pragma unroll
      for (int nt = 0; nt < 4; nt++)
        #pragma unroll
        for (int ks = 0; ks < 2; ks++)
          acc[mt][nt] = __builtin_amdgcn_mfma_f32_16x16x32_bf16(
              af[mt][ks], bf[nt][ks], acc[mt][nt], 0, 0, 0);
  }

  if (EPI == 0) {
    const int nbase = bn * 128 + wn * 64;
    if (bn < 8) {
      // q (scaled by log2e/8) or k, with bias + RoPE
      const float scl = (bn < 7) ? (0.125f * LOG2E) : 1.0f;
      const float* bias = (bn < 7) ? biasq : (biask - 896);
      #pragma unroll
      for (int mt = 0; mt < 4; mt++) {
        const int m0 = bm * 128 + wm * 64 + mt * 16 + rg * 4;
        #pragma unroll
        for (int nt = 0; nt < 4; nt++) {
          int n = nbase + nt * 16 + r16;
          int j = n & 31;
          float sgn = (n & 32) ? 1.f : -1.f;
          float b0 = bias[n], b1 = bias[n ^ 32];
          #pragma unroll
          for (int r = 0; r < 4; r++) {
            int m = m0 + r;
            float c_ = cost[m * 32 + j], s_ = sint[m * 32 + j];
            float val = ((acc[mt][nt][r] + b0) * c_ +
                         sgn * (acc[mt][nt ^ 2][r] + b1) * s_) * scl;
            qkb[(size_t)m * NQK + n] = f2bf(val);
          }
        }
      }
    } else {
      // v -> vtb [128][4096] transposed
      #pragma unroll
      for (int mt = 0; mt < 4; mt++) {
        const int m0 = bm * 128 + wm * 64 + mt * 16 + rg * 4;
        #pragma unroll
        for (int nt = 0; nt < 4; nt++) {
          int vc = wn * 64 + nt * 16 + r16;
          float b0 = biasv[vc];
          bf16x4 pk;
          #pragma unroll
          for (int r = 0; r < 4; r++) pk[r] = f2bf(acc[mt][nt][r] + b0);
          *(bf16x4*)&vtb[(size_t)vc * S_ + m0] = pk;
        }
      }
    }
  } else {
    #pragma unroll
    for (int mt = 0; mt < 4; mt++) {
      const int m0 = bm * 128 + wm * 64 + mt * 16 + rg * 4;
      #pragma unroll
      for (int nt = 0; nt < 4; nt++) {
        int n = bn * 128 + wn * 64 + nt * 16 + r16;
        #pragma unroll
        for (int r = 0; r < 4; r++)
          outp[(size_t)(m0 + r) * NQ + n] = acc[mt][nt][r];
      }
    }
  }
}

// ---------------------------------------------------------------------------
// Flash attention v3: QBLK=128, KBLK=128, grid (16,14) -- block p handles
// q-tiles (31-p) then (p): every block does exactly 33 K-iterations.
// 8 waves = 4 m-groups (32 rows) x 2 key-halves (64 keys); per-half private
// online softmax state, merged once per q-tile through LDS.
// Raw s_barrier + lgkmcnt-only waits so prefetch global loads stay in flight.
// ---------------------------------------------------------------------------
__global__ __launch_bounds__(512) void flash_mfma(
    const short* __restrict__ qkb, const short* __restrict__ vtb,
    short* __restrict__ attnb)
{
  __shared__ __align__(16) char lds[65536];
  char* KsB = lds;             // [128 keys][64 hd]  bf16, 128B rows, 16 KB
  char* VtB = lds + 16384;     // [64 hd][128 keys]  bf16, 256B rows, 16 KB
  char* PsB = lds + 32768;     // 8 waves x 4 KB ( [2 mt][16 rows][128B] )

  const int tid  = threadIdx.x;
  const int lane = tid & 63;
  const int w    = tid >> 6;
  const int r16  = lane & 15;
  const int rg   = lane >> 4;
  const int mg   = w & 3;       // m-group: rows mg*32
  const int nh   = w >> 2;      // key half: keys nh*64
  const int h    = blockIdx.y;
  const int kv   = h / GROUPS;
  const int p    = blockIdx.x;
  char* Pw = PsB + w * 4096;
  const int kbase = NQ + kv * HDim;

  // staging mapping (512 threads, 2 chunks each for K and V)
  const int krow = tid >> 3;           // 0..63 (and +64)
  const int kc8  = tid & 7;
  const int vhd  = tid >> 4;           // 0..31 (and +32)
  const int vc16 = tid & 15;
  const int kdst0 = krow * 128 + ((kc8 * 16) ^ ((krow & 7) << 4));
  const int kdst1 = kdst0 + 64 * 128;  // (krow+64)&7 == krow&7
  const int vdst0 = vhd * 256 + ((vc16 * 16) ^ ((vhd & 7) << 4));
  const int vdst1 = vdst0 + 32 * 256;  // (vhd+32)&7 == vhd&7

  bf16x8 ones;
  #pragma unroll
  for (int j = 0; j < 8; j++) ones[j] = (short)0x3F80;  // bf16(1.0)
  const f32x4 zero4 = {0.f, 0.f, 0.f, 0.f};

  for (int hf = 0; hf < 2; ++hf) {
    const int qt = hf ? p : (31 - p);
    const int q0 = qt * 128;

    // Q fragments (Q already scaled by log2e/8)
    bf16x8 aq[2][2];
    #pragma unroll
    for (int mt = 0; mt < 2; ++mt) {
      const short* qp = qkb + (size_t)(q0 + mg * 32 + mt * 16 + r16) * NQK + h * HDim + rg * 8;
      aq[mt][0] = *(const bf16x8*)qp;
      aq[mt][1] = *(const bf16x8*)(qp + 32);
    }

    f32x4 acc_o[2][4];
    f32x4 acc_l[2];
    float mrow[2][4];
    #pragma unroll
    for (int mt = 0; mt < 2; mt++) {
      acc_l[mt] = zero4;
      #pragma unroll
      for (int nt = 0; nt < 4; nt++) acc_o[mt][nt] = zero4;
      #pragma unroll
      for (int r = 0; r < 4; r++) mrow[mt][r] = 0.0f;   // safe ref point
    }

    // prologue: load tile 0 into regs
    bf16x8 kr0, kr1, vr0, vr1;
    {
      const short* kp = qkb + (size_t)(0 * 128 + krow) * NQK + kbase + kc8 * 8;
      kr0 = *(const bf16x8*)kp;
      kr1 = *(const bf16x8*)(kp + (size_t)64 * NQK);
      const short* vp = vtb + (size_t)(kv * 64 + vhd) * S_ + 0 * 128 + vc16 * 8;
      vr0 = *(const bf16x8*)vp;
      vr1 = *(const bf16x8*)(vp + (size_t)32 * S_);
    }

    for (int kt = 0; kt <= qt; ++kt) {
      // issue next tile's loads first (hidden under this tile's compute)
      bf16x8 nk0, nk1, nv0, nv1;
      if (kt < qt) {
        const short* kp = qkb + (size_t)((kt + 1) * 128 + krow) * NQK + kbase + kc8 * 8;
        nk0 = *(const bf16x8*)kp;
        nk1 = *(const bf16x8*)(kp + (size_t)64 * NQK);
        const short* vp = vtb + (size_t)(kv * 64 + vhd) * S_ + (kt + 1) * 128 + vc16 * 8;
        nv0 = *(const bf16x8*)vp;
        nv1 = *(const bf16x8*)(vp + (size_t)32 * S_);
      }
      // stage current tile
      *(bf16x8*)(KsB + kdst0) = kr0;
      *(bf16x8*)(KsB + kdst1) = kr1;
      *(bf16x8*)(VtB + vdst0) = vr0;
      *(bf16x8*)(VtB + vdst1) = vr1;
      if (kt < qt) { kr0 = nk0; kr1 = nk1; vr0 = nv0; vr1 = nv1; }
      asm volatile("s_waitcnt lgkmcnt(0)" ::: "memory");
      __builtin_amdgcn_s_barrier();

      // S = Q K^T over this wave's 64-key half
      f32x4 sc[2][4];
      #pragma unroll
      for (int mt = 0; mt < 2; mt++)
        #pragma unroll
        for (int nt = 0; nt < 4; nt++) sc[mt][nt] = zero4;
      #pragma unroll
      for (int nt = 0; nt < 4; ++nt) {
        int key = nh * 64 + nt * 16 + r16;
        #pragma unroll
        for (int ks = 0; ks < 2; ++ks) {
          bf16x8 bk = *(const bf16x8*)(KsB + key * 128 +
                        (((ks * 4 + rg) * 16) ^ ((key & 7) << 4)));
          sc[0][nt] = __builtin_amdgcn_mfma_f32_16x16x32_bf16(aq[0][ks], bk, sc[0][nt], 0, 0, 0);
          sc[1][nt] = __builtin_amdgcn_mfma_f32_16x16x32_bf16(aq[1][ks], bk, sc[1][nt], 0, 0, 0);
        }
      }

      // online softmax (exp2 domain) per m-tile
      const int kc0 = kt * 128 + nh * 64;
      #pragma unroll
      for (int mt = 0; mt < 2; ++mt) {
        const int rowbase = q0 + mg * 32 + mt * 16;
        const bool domask = (kc0 + 63) > rowbase;
        float pexp[4][4];
        #pragma unroll
        for (int r = 0; r < 4; ++r) {
          int qg = rowbase + rg * 4 + r;
          float s0 = sc[mt][0][r], s1 = sc[mt][1][r], s2 = sc[mt][2][r], s3 = sc[mt][3][r];
          if (domask) {
            int kg = kc0 + r16;
            s0 = (kg      > qg) ? -1e30f : s0;
            s1 = (kg + 16 > qg) ? -1e30f : s1;
            s2 = (kg + 32 > qg) ? -1e30f : s2;
            s3 = (kg + 48 > qg) ? -1e30f : s3;
          }
          float mx = red_max16(fmaxf(fmaxf(s0, s1), fmaxf(s2, s3)));
          float newm = fmaxf(mrow[mt][r], mx);
          float scl = exp2f(mrow[mt][r] - newm);
          mrow[mt][r] = newm;
          pexp[0][r] = exp2f(s0 - newm);
          pexp[1][r] = exp2f(s1 - newm);
          pexp[2][r] = exp2f(s2 - newm);
          pexp[3][r] = exp2f(s3 - newm);
          acc_l[mt][r] *= scl;
          #pragma unroll
          for (int nt = 0; nt < 4; nt++) acc_o[mt][nt][r] *= scl;
        }
        #pragma unroll
        for (int nt = 0; nt < 4; nt++)
          #pragma unroll
          for (int r = 0; r < 4; r++) {
            int prow = rg * 4 + r;
            *(short*)(Pw + mt * 2048 + prow * 128 +
                      ((nt * 32 + r16 * 2) ^ ((prow & 7) << 4))) = f2bf(pexp[nt][r]);
          }
      }

      // O += P V ; l += P . 1  (wave-private P; DS in-order per wave)
      #pragma unroll
      for (int ks = 0; ks < 2; ++ks) {
        int pch = ((ks * 4 + rg) * 16) ^ ((r16 & 7) << 4);
        bf16x8 ap0 = *(const bf16x8*)(Pw +        r16 * 128 + pch);
        bf16x8 ap1 = *(const bf16x8*)(Pw + 2048 + r16 * 128 + pch);
        acc_l[0] = __builtin_amdgcn_mfma_f32_16x16x32_bf16(ap0, ones, acc_l[0], 0, 0, 0);
        acc_l[1] = __builtin_amdgcn_mfma_f32_16x16x32_bf16(ap1, ones, acc_l[1], 0, 0, 0);
        #pragma unroll
        for (int nt = 0; nt < 4; ++nt) {
          int hd = nt * 16 + r16;
          bf16x8 bv = *(const bf16x8*)(VtB + hd * 256 +
                        (((nh * 8 + ks * 4 + rg) * 16) ^ ((hd & 7) << 4)));
          acc_o[0][nt] = __builtin_amdgcn_mfma_f32_16x16x32_bf16(ap0, bv, acc_o[0][nt], 0, 0, 0);
          acc_o[1][nt] = __builtin_amdgcn_mfma_f32_16x16x32_bf16(ap1, bv, acc_o[1][nt], 0, 0, 0);
        }
      }
      __builtin_amdgcn_s_barrier();   // reads done before next staging
    }

    // --- merge the two key-halves (through LDS, once per q-tile) ---
    char* db = lds + mg * 12288;
    if (nh == 1) {
      #pragma unroll
      for (int mt = 0; mt < 2; mt++)
        #pragma unroll
        for (int nt = 0; nt < 4; nt++)
          *(f32x4*)(db + (mt * 4 + nt) * 1024 + lane * 16) = acc_o[mt][nt];
      *(f32x4*)(db + 8 * 1024 + lane * 16) = acc_l[0];
      *(f32x4*)(db + 9 * 1024 + lane * 16) = acc_l[1];
      f32x4 mv0 = {mrow[0][0], mrow[0][1], mrow[0][2], mrow[0][3]};
      f32x4 mv1 = {mrow[1][0], mrow[1][1], mrow[1][2], mrow[1][3]};
      *(f32x4*)(db + 10 * 1024 + lane * 16) = mv0;
      *(f32x4*)(db + 11 * 1024 + lane * 16) = mv1;
    }
    asm volatile("s_waitcnt lgkmcnt(0)" ::: "memory");
    __builtin_amdgcn_s_barrier();
    if (nh == 0) {
      f32x4 d[12];
      #pragma unroll
      for (int i = 0; i < 12; i++) d[i] = *(const f32x4*)(db + i * 1024 + lane * 16);
      #pragma unroll
      for (int mt = 0; mt < 2; mt++)
        #pragma unroll
        for (int r = 0; r < 4; r++) {
          float m1 = mrow[mt][r], m2 = d[10 + mt][r];
          float M  = fmaxf(m1, m2);
          float a1 = exp2f(m1 - M), a2 = exp2f(m2 - M);
          float l  = a1 * acc_l[mt][r] + a2 * d[8 + mt][r];
          float inv = 1.0f / l;
          int qg = q0 + mg * 32 + mt * 16 + rg * 4 + r;
          short* op = attnb + (size_t)qg * NQ + h * HDim + r16;
          #pragma unroll
          for (int nt = 0; nt < 4; nt++)
            op[nt * 16] = f2bf((a1 * acc_o[mt][nt][r] + a2 * d[mt * 4 + nt][r]) * inv);
        }
    }
    __builtin_amdgcn_s_barrier();   // merge reads done before next half stages
  }
}

// ---------------------------------------------------------------------------
extern "C" void kernel_launch(void* const* d_in, const int* in_sizes, int n_in,
                              void* d_out, int out_size, void* d_ws, size_t ws_size,
                              hipStream_t stream)
{
  const float* hs = (const float*)d_in[0];
  // d_in[1] = attention_mask (exactly causal; handled analytically)
  const float* Wq = (const float*)d_in[2];
  const float* bq = (const float*)d_in[3];
  const float* Wk = (const float*)d_in[4];
  const float* bk = (const float*)d_in[5];
  const float* Wv = (const float*)d_in[6];
  const float* bv = (const float*)d_in[7];
  const float* Wo = (const float*)d_in[8];

  short* hsb  = (short*)d_ws;                     // [4096][896]  bf16
  short* wtq  = hsb + (size_t)S_ * Dm;            // [1152][896]  bf16
  short* wto  = wtq + (size_t)1152 * 896;         // [896][896]   bf16
  float* cost = (float*)(wto + (size_t)896 * 896);// [4096][32]   f32
  float* sint = cost + (size_t)S_ * 32;           // [4096][32]   f32
  short* qkb  = (short*)(sint + (size_t)S_ * 32); // [4096][1024] bf16
  short* vtb  = qkb + (size_t)S_ * NQK;           // [128][4096]  bf16 (V^T)
  short* attnb= vtb + (size_t)NK * S_;            // [4096][896]  bf16
  float* out  = (float*)d_out;

  hipLaunchKernelGGL(cvt_hs,   dim3(S_ * Dm / 8 / 256), dim3(256), 0, stream, hs, hsb);
  hipLaunchKernelGGL(rope_tab, dim3(S_ * 32 / 256),     dim3(256), 0, stream, cost, sint);
  hipLaunchKernelGGL(transpose_w, dim3(14, 14), dim3(256), 0, stream, Wq, NQ, wtq, 0);
  hipLaunchKernelGGL(transpose_w, dim3(14, 2),  dim3(256), 0, stream, Wk, NK, wtq, 896);
  hipLaunchKernelGGL(transpose_w, dim3(14, 2),  dim3(256), 0, stream, Wv, NK, wtq, 1024);
  hipLaunchKernelGGL(transpose_w, dim3(14, 14), dim3(256), 0, stream, Wo, NQ, wto, 0);

  hipLaunchKernelGGL((gemm128<0>), dim3(32, 9), dim3(256), 0, stream,
                     hsb, wtq, bq, bk, bv, cost, sint, qkb, vtb, (float*)nullptr);
  hipLaunchKernelGGL(flash_mfma, dim3(16, NHd), dim3(512), 0, stream,
                     qkb, vtb, attnb);
  hipLaunchKernelGGL((gemm128<1>), dim3(32, 7), dim3(256), 0, stream,
                     attnb, wto, bq, bk, bv, cost, sint,
                     (short*)nullptr, (short*)nullptr, out);
}